// Round 15
// baseline (351.483 us; speedup 1.0000x reference)
//
#include <hip/hip_runtime.h>

#define HD 64
#define FC 16
#define FEMB 8

__device__ __forceinline__ float bfu(unsigned u) { return __uint_as_float(u); }
__device__ __forceinline__ unsigned short f2bf(float f) {
    unsigned u = __float_as_uint(f);
    return (unsigned short)((u + 0x7fffu + ((u >> 16) & 1u)) >> 16);  // RNE
}

// ---- pass 1: count + rank. 4 edges/thread, 4 independent atomic returns ----
__global__ void k_count_rank(const int* __restrict__ dst, int* __restrict__ cnt,
                             int* __restrict__ rank, int E) {
    int t = blockIdx.x * blockDim.x + threadIdx.x;
    int base = t * 4;
    if (base + 4 <= E) {
        int4 d = *(const int4*)(dst + base);
        int r0 = atomicAdd(&cnt[d.x], 1);
        int r1 = atomicAdd(&cnt[d.y], 1);
        int r2 = atomicAdd(&cnt[d.z], 1);
        int r3 = atomicAdd(&cnt[d.w], 1);
        *(int4*)(rank + base) = make_int4(r0, r1, r2, r3);
    } else {
        for (int e = base; e < E; e++)
            rank[e] = atomicAdd(&cnt[dst[e]], 1);
    }
}

// ---- scan phase 1: per-block exclusive scan of cnt; also disq ----
__global__ void k_scan1(const int* __restrict__ cnt, int* __restrict__ row_part,
                        int* __restrict__ bsum, float* __restrict__ disq, int n) {
    __shared__ int s[256];
    int t = threadIdx.x;
    int i = blockIdx.x * 256 + t;
    int v = (i < n) ? cnt[i] : 0;
    if (i < n) disq[i] = rsqrtf(1.0f + (float)v);
    s[t] = v;
    __syncthreads();
    for (int off = 1; off < 256; off <<= 1) {
        int a = (t >= off) ? s[t - off] : 0;
        __syncthreads();
        s[t] += a;
        __syncthreads();
    }
    if (i < n) row_part[i] = s[t] - v;
    if (t == 255) bsum[blockIdx.x] = s[255];
}

// ---- scan phase 2: exclusive scan of block sums (single block) ----
__global__ void k_scan2(int* __restrict__ bsum, int nb) {
    __shared__ int s[1024];
    int t = threadIdx.x;
    int v = (t < nb) ? bsum[t] : 0;
    s[t] = v;
    __syncthreads();
    for (int off = 1; off < 1024; off <<= 1) {
        int a = (t >= off) ? s[t - off] : 0;
        __syncthreads();
        s[t] += a;
        __syncthreads();
    }
    if (t < nb) bsum[t] = s[t] - v;
}

// ---- fused: XCD-partitioned rank-based reorder (blocks [0,nbr)) + input ----
__global__ void k_reorder_input(const int* __restrict__ src, const int* __restrict__ dst,
                                const int* __restrict__ rank, const int* __restrict__ row_part,
                                const int* __restrict__ bsum, int* __restrict__ csr, int E,
                                int nbr,
                                const float* __restrict__ xc, const int* __restrict__ ft,
                                const float* __restrict__ emb, const float* __restrict__ Win,
                                const float* __restrict__ bin, const float* __restrict__ disq,
                                unsigned short* __restrict__ y, int n) {
    int b = blockIdx.x;
    if (b < nbr) {
        int g   = b & 7;
        int bg  = b >> 3;
        int nbg = nbr >> 3;
        int slice = n >> 3;
        int lo = g * slice;
        int hi = (g == 7) ? n : lo + slice;
        int stride = nbg * 256;
        for (int e = bg * 256 + (int)threadIdx.x; e < E; e += stride) {
            int d = dst[e];
            if (d >= lo && d < hi) {
                int pos = row_part[d] + bsum[d >> 8] + rank[e];
                csr[pos] = src[e];
            }
        }
    } else {
        int lane = threadIdx.x & 63;
        int wid  = (((b - nbr) * 256 + (int)threadIdx.x) >> 6);
        if (wid >= n) return;
        float acc = bin[lane];
        const float* xr = xc + (size_t)wid * FC;
#pragma unroll
        for (int k = 0; k < FC; k++)
            acc = fmaf(xr[k], Win[k * HD + lane], acc);
        int t = ft[wid];
        const float* er = emb + (size_t)t * FEMB;
#pragma unroll
        for (int k = 0; k < FEMB; k++)
            acc = fmaf(er[k], Win[(FC + k) * HD + lane], acc);
        y[(size_t)wid * HD + lane] = f2bf(fmaxf(acc, 0.0f) * disq[wid]);
    }
}

// ---- aggregation: agg_i = disq_i * (y_i + sum_{j in N(i)} y_j)   [y is bf16] ----
// one wave per node; 4 subgroups x 16 lanes, each lane uint2 (4 bf16) -> 128B row.
// Chunk = 16 edges = 4 independent load slots PER LANE (deep MLP); clamped slots
// fetch a duplicate line (coalesced, ~free) and are masked out of the sum.
__global__ void k_agg(const uint2* __restrict__ y2, const int* __restrict__ csr,
                      const int* __restrict__ row_part, const int* __restrict__ bsum,
                      const int* __restrict__ cnt,
                      const float* __restrict__ disq, float* __restrict__ agg, int n) {
    int lane = threadIdx.x & 63;
    int node = (blockIdx.x * blockDim.x + threadIdx.x) >> 6;
    if (node >= n) return;
    int g  = lane >> 4;   // edge subgroup 0..3
    int c2 = lane & 15;   // uint2 column (4 bf16 per lane)
    int start = row_part[node] + bsum[node >> 8];
    int deg   = cnt[node];
    int end   = start + deg;
    float di  = disq[node];
    float a0 = 0.f, a1 = 0.f, a2 = 0.f, a3 = 0.f;
    for (int j = start; j < end; j += 16) {
#pragma unroll
        for (int slot = 0; slot < 4; slot++) {
            int e = j + slot * 4 + g;
            bool ok = e < end;
            int s = csr[ok ? e : j];
            uint2 v = y2[(size_t)s * 16 + c2];
            if (ok) {
                a0 += bfu(v.x << 16); a1 += bfu(v.x & 0xffff0000u);
                a2 += bfu(v.y << 16); a3 += bfu(v.y & 0xffff0000u);
            }
        }
    }
    // reduce over the 4 edge subgroups (lane bits 4,5)
    a0 += __shfl_xor(a0, 16); a1 += __shfl_xor(a1, 16);
    a2 += __shfl_xor(a2, 16); a3 += __shfl_xor(a3, 16);
    a0 += __shfl_xor(a0, 32); a1 += __shfl_xor(a1, 32);
    a2 += __shfl_xor(a2, 32); a3 += __shfl_xor(a3, 32);
    if (g == 0) {
        uint2 sv = y2[(size_t)node * 16 + c2];
        a0 += bfu(sv.x << 16); a1 += bfu(sv.x & 0xffff0000u);
        a2 += bfu(sv.y << 16); a3 += bfu(sv.y & 0xffff0000u);
        float4 o = {di * a0, di * a1, di * a2, di * a3};
        *(float4*)(agg + (size_t)node * HD + c2 * 4) = o;
    }
}

// ---- tiled matmul: y16 = bf16( disq * relu(agg @ W + b) ) ----
__global__ __launch_bounds__(256, 4)
void k_mm(const float* __restrict__ x, const float* __restrict__ W,
          const float* __restrict__ b, const float* __restrict__ disq,
          unsigned short* __restrict__ yo, int n) {
    __shared__ float4 ws4[64][16];
    __shared__ float4 xs4[64][17];
    int tid = threadIdx.x;
    int node0 = blockIdx.x * 64;

    for (int i = tid; i < 1024; i += 256)
        ws4[i >> 4][i & 15] = ((const float4*)W)[i];
    for (int i = tid; i < 1024; i += 256) {
        int nn = i >> 4, k4 = i & 15;
        int row = node0 + nn; if (row >= n) row = n - 1;
        xs4[nn][k4] = ((const float4*)(x + (size_t)row * HD))[k4];
    }
    __syncthreads();

    int tc4 = tid & 15;
    int tn  = (tid >> 4) * 4;
    float4 ac0 = {0,0,0,0}, ac1 = {0,0,0,0}, ac2 = {0,0,0,0}, ac3 = {0,0,0,0};

#pragma unroll 4
    for (int k4 = 0; k4 < 16; k4++) {
        float4 w0 = ws4[k4 * 4 + 0][tc4];
        float4 w1 = ws4[k4 * 4 + 1][tc4];
        float4 w2 = ws4[k4 * 4 + 2][tc4];
        float4 w3 = ws4[k4 * 4 + 3][tc4];
#pragma unroll
        for (int i = 0; i < 4; i++) {
            float4 xv = xs4[tn + i][k4];
            float4* ac = (i == 0) ? &ac0 : (i == 1) ? &ac1 : (i == 2) ? &ac2 : &ac3;
            ac->x = fmaf(xv.x, w0.x, ac->x); ac->y = fmaf(xv.x, w0.y, ac->y);
            ac->z = fmaf(xv.x, w0.z, ac->z); ac->w = fmaf(xv.x, w0.w, ac->w);
            ac->x = fmaf(xv.y, w1.x, ac->x); ac->y = fmaf(xv.y, w1.y, ac->y);
            ac->z = fmaf(xv.y, w1.z, ac->z); ac->w = fmaf(xv.y, w1.w, ac->w);
            ac->x = fmaf(xv.z, w2.x, ac->x); ac->y = fmaf(xv.z, w2.y, ac->y);
            ac->z = fmaf(xv.z, w2.z, ac->z); ac->w = fmaf(xv.z, w2.w, ac->w);
            ac->x = fmaf(xv.w, w3.x, ac->x); ac->y = fmaf(xv.w, w3.y, ac->y);
            ac->z = fmaf(xv.w, w3.z, ac->z); ac->w = fmaf(xv.w, w3.w, ac->w);
        }
    }

    float4 bb = ((const float4*)b)[tc4];
    float4 accs[4] = {ac0, ac1, ac2, ac3};
#pragma unroll
    for (int i = 0; i < 4; i++) {
        int row = node0 + tn + i;
        if (row < n) {
            float dq = disq[row];
            ushort4 o;
            o.x = f2bf(fmaxf(accs[i].x + bb.x, 0.0f) * dq);
            o.y = f2bf(fmaxf(accs[i].y + bb.y, 0.0f) * dq);
            o.z = f2bf(fmaxf(accs[i].z + bb.z, 0.0f) * dq);
            o.w = f2bf(fmaxf(accs[i].w + bb.w, 0.0f) * dq);
            *(ushort4*)(yo + (size_t)row * HD + tc4 * 4) = o;
        }
    }
}

// ---- fused layer-3 matmul + head (reads fp32 agg) ----
__global__ __launch_bounds__(256, 4)
void k_mm_head(const float* __restrict__ x, const float* __restrict__ W,
               const float* __restrict__ b, const float* __restrict__ W1,
               const float* __restrict__ b1, const float* __restrict__ W2,
               const float* __restrict__ b2, float* __restrict__ out, int n) {
    __shared__ float4 ws4[64][16];
    __shared__ float4 xs4[64][17];
    int tid = threadIdx.x;
    int node0 = blockIdx.x * 64;

    for (int i = tid; i < 1024; i += 256)
        ws4[i >> 4][i & 15] = ((const float4*)W)[i];
    for (int i = tid; i < 1024; i += 256) {
        int nn = i >> 4, k4 = i & 15;
        int row = node0 + nn; if (row >= n) row = n - 1;
        xs4[nn][k4] = ((const float4*)(x + (size_t)row * HD))[k4];
    }
    __syncthreads();

    int tc4 = tid & 15;
    int tn  = (tid >> 4) * 4;

    float4 ac0 = {0,0,0,0}, ac1 = {0,0,0,0}, ac2 = {0,0,0,0}, ac3 = {0,0,0,0};
#pragma unroll 4
    for (int k4 = 0; k4 < 16; k4++) {
        float4 w0 = ws4[k4 * 4 + 0][tc4];
        float4 w1 = ws4[k4 * 4 + 1][tc4];
        float4 w2 = ws4[k4 * 4 + 2][tc4];
        float4 w3 = ws4[k4 * 4 + 3][tc4];
#pragma unroll
        for (int i = 0; i < 4; i++) {
            float4 xv = xs4[tn + i][k4];
            float4* ac = (i == 0) ? &ac0 : (i == 1) ? &ac1 : (i == 2) ? &ac2 : &ac3;
            ac->x = fmaf(xv.x, w0.x, ac->x); ac->y = fmaf(xv.x, w0.y, ac->y);
            ac->z = fmaf(xv.x, w0.z, ac->z); ac->w = fmaf(xv.x, w0.w, ac->w);
            ac->x = fmaf(xv.y, w1.x, ac->x); ac->y = fmaf(xv.y, w1.y, ac->y);
            ac->z = fmaf(xv.y, w1.z, ac->z); ac->w = fmaf(xv.y, w1.w, ac->w);
            ac->x = fmaf(xv.z, w2.x, ac->x); ac->y = fmaf(xv.z, w2.y, ac->y);
            ac->z = fmaf(xv.z, w2.z, ac->z); ac->w = fmaf(xv.z, w2.w, ac->w);
            ac->x = fmaf(xv.w, w3.x, ac->x); ac->y = fmaf(xv.w, w3.y, ac->y);
            ac->z = fmaf(xv.w, w3.z, ac->z); ac->w = fmaf(xv.w, w3.w, ac->w);
        }
    }
    __syncthreads();

    {
        float4 bb = ((const float4*)b)[tc4];
        float4 accs[4] = {ac0, ac1, ac2, ac3};
#pragma unroll
        for (int i = 0; i < 4; i++) {
            float4 o;
            o.x = fmaxf(accs[i].x + bb.x, 0.0f);
            o.y = fmaxf(accs[i].y + bb.y, 0.0f);
            o.z = fmaxf(accs[i].z + bb.z, 0.0f);
            o.w = fmaxf(accs[i].w + bb.w, 0.0f);
            xs4[tn + i][tc4] = o;
        }
    }
    for (int i = tid; i < 1024; i += 256)
        ws4[i >> 4][i & 15] = ((const float4*)W1)[i];
    __syncthreads();

    float4 bc0 = {0,0,0,0}, bc1 = {0,0,0,0}, bc2 = {0,0,0,0}, bc3 = {0,0,0,0};
#pragma unroll 4
    for (int k4 = 0; k4 < 16; k4++) {
        float4 w0 = ws4[k4 * 4 + 0][tc4];
        float4 w1 = ws4[k4 * 4 + 1][tc4];
        float4 w2 = ws4[k4 * 4 + 2][tc4];
        float4 w3 = ws4[k4 * 4 + 3][tc4];
#pragma unroll
        for (int i = 0; i < 4; i++) {
            float4 xv = xs4[tn + i][k4];
            float4* ac = (i == 0) ? &bc0 : (i == 1) ? &bc1 : (i == 2) ? &bc2 : &bc3;
            ac->x = fmaf(xv.x, w0.x, ac->x); ac->y = fmaf(xv.x, w0.y, ac->y);
            ac->z = fmaf(xv.x, w0.z, ac->z); ac->w = fmaf(xv.x, w0.w, ac->w);
            ac->x = fmaf(xv.y, w1.x, ac->x); ac->y = fmaf(xv.y, w1.y, ac->y);
            ac->z = fmaf(xv.y, w1.z, ac->z); ac->w = fmaf(xv.y, w1.w, ac->w);
            ac->x = fmaf(xv.z, w2.x, ac->x); ac->y = fmaf(xv.z, w2.y, ac->y);
            ac->z = fmaf(xv.z, w2.z, ac->z); ac->w = fmaf(xv.z, w2.w, ac->w);
            ac->x = fmaf(xv.w, w3.x, ac->x); ac->y = fmaf(xv.w, w3.y, ac->y);
            ac->z = fmaf(xv.w, w3.z, ac->z); ac->w = fmaf(xv.w, w3.w, ac->w);
        }
    }

    float4 b1v = ((const float4*)b1)[tc4];
    float4 w2v = ((const float4*)W2)[tc4];
    float b2v  = b2[0];
    float4 bcs[4] = {bc0, bc1, bc2, bc3};
#pragma unroll
    for (int i = 0; i < 4; i++) {
        float s = fmaxf(bcs[i].x + b1v.x, 0.0f) * w2v.x
                + fmaxf(bcs[i].y + b1v.y, 0.0f) * w2v.y
                + fmaxf(bcs[i].z + b1v.z, 0.0f) * w2v.z
                + fmaxf(bcs[i].w + b1v.w, 0.0f) * w2v.w;
        s += __shfl_xor(s, 1);
        s += __shfl_xor(s, 2);
        s += __shfl_xor(s, 4);
        s += __shfl_xor(s, 8);
        int row = node0 + tn + i;
        if (tc4 == 0 && row < n) out[row] = s + b2v;
    }
}

extern "C" void kernel_launch(void* const* d_in, const int* in_sizes, int n_in,
                              void* d_out, int out_size, void* d_ws, size_t ws_size,
                              hipStream_t stream) {
    const float* x_cont = (const float*)d_in[0];
    const int*   ftyp   = (const int*)d_in[1];
    const int*   eidx   = (const int*)d_in[2];
    const float* emb    = (const float*)d_in[3];
    const float* W_in   = (const float*)d_in[4];
    const float* b_in   = (const float*)d_in[5];
    const float* W_g    = (const float*)d_in[6];
    const float* b_g    = (const float*)d_in[7];
    const float* W_o1   = (const float*)d_in[8];
    const float* b_o1   = (const float*)d_in[9];
    const float* W_o2   = (const float*)d_in[10];
    const float* b_o2   = (const float*)d_in[11];
    float* out = (float*)d_out;

    const int n = in_sizes[1];
    const int E = in_sizes[2] / 2;
    const int* src = eidx;
    const int* dst = eidx + E;

    char* p = (char*)d_ws;
    auto alloc = [&](size_t bytes) {
        char* r = p;
        p += (bytes + 255) & ~(size_t)255;
        return r;
    };
    int*      cnt      = (int*)  alloc((size_t)n * 4);
    float*    disq     = (float*)alloc((size_t)n * 4);
    int*      row_part = (int*)  alloc((size_t)n * 4);
    int*      bsum     = (int*)  alloc(4096);
    int*      rank     = (int*)  alloc((size_t)E * 4);
    int*      csr      = (int*)  alloc((size_t)E * 4);
    unsigned short* y16 = (unsigned short*)alloc((size_t)n * HD * 2);
    float*    agg      = (float*)alloc((size_t)n * HD * 4);

    hipMemsetAsync(cnt, 0, (size_t)n * 4, stream);

    dim3 blk(256);
    const int nb1   = (n + 255) / 256;
    const int nb_c  = (E / 4 + 255) / 256;  // 4 edges per thread
    const int nbr   = 2048;                 // 8 XCD groups x 256 blocks
    const int nb_nw = (n + 3) / 4;          // one wave per node
    const int nb_t  = (n + 63) / 64;        // 64-node tiles

    k_count_rank<<<nb_c, blk, 0, stream>>>(dst, cnt, rank, E);
    k_scan1<<<nb1, blk, 0, stream>>>(cnt, row_part, bsum, disq, n);
    k_scan2<<<1, 1024, 0, stream>>>(bsum, nb1);
    k_reorder_input<<<nbr + nb_nw, blk, 0, stream>>>(
        src, dst, rank, row_part, bsum, csr, E, nbr,
        x_cont, ftyp, emb, W_in, b_in, disq, y16, n);

    for (int L = 0; L < 2; L++) {
        k_agg<<<nb_nw, blk, 0, stream>>>((const uint2*)y16, csr, row_part, bsum,
                                         cnt, disq, agg, n);
        k_mm<<<nb_t, blk, 0, stream>>>(agg, W_g + (size_t)L * HD * HD,
                                       b_g + (size_t)L * HD, disq, y16, n);
    }
    k_agg<<<nb_nw, blk, 0, stream>>>((const uint2*)y16, csr, row_part, bsum,
                                     cnt, disq, agg, n);
    k_mm_head<<<nb_t, blk, 0, stream>>>(agg, W_g + (size_t)2 * HD * HD,
                                        b_g + (size_t)2 * HD,
                                        W_o1, b_o1, W_o2, b_o2, out, n);
}

// Round 16
// 319.605 us; speedup vs baseline: 1.0997x; 1.0997x over previous
//
#include <hip/hip_runtime.h>

#define HD 64
#define FC 16
#define FEMB 8

__device__ __forceinline__ float bfu(unsigned u) { return __uint_as_float(u); }
__device__ __forceinline__ unsigned short f2bf(float f) {
    unsigned u = __float_as_uint(f);
    return (unsigned short)((u + 0x7fffu + ((u >> 16) & 1u)) >> 16);  // RNE
}

// ---- pass 1: count + rank ----
__global__ void k_count_rank(const int* __restrict__ dst, int* __restrict__ cnt,
                             int* __restrict__ rank, int E) {
    int e = blockIdx.x * blockDim.x + threadIdx.x;
    if (e >= E) return;
    rank[e] = atomicAdd(&cnt[dst[e]], 1);
}

// ---- scan phase 1 ----
__global__ void k_scan1(const int* __restrict__ cnt, int* __restrict__ row_part,
                        int* __restrict__ bsum, float* __restrict__ disq, int n) {
    __shared__ int s[256];
    int t = threadIdx.x;
    int i = blockIdx.x * 256 + t;
    int v = (i < n) ? cnt[i] : 0;
    if (i < n) disq[i] = rsqrtf(1.0f + (float)v);
    s[t] = v;
    __syncthreads();
    for (int off = 1; off < 256; off <<= 1) {
        int a = (t >= off) ? s[t - off] : 0;
        __syncthreads();
        s[t] += a;
        __syncthreads();
    }
    if (i < n) row_part[i] = s[t] - v;
    if (t == 255) bsum[blockIdx.x] = s[255];
}

// ---- scan phase 2 ----
__global__ void k_scan2(int* __restrict__ bsum, int nb) {
    __shared__ int s[1024];
    int t = threadIdx.x;
    int v = (t < nb) ? bsum[t] : 0;
    s[t] = v;
    __syncthreads();
    for (int off = 1; off < 1024; off <<= 1) {
        int a = (t >= off) ? s[t - off] : 0;
        __syncthreads();
        s[t] += a;
        __syncthreads();
    }
    if (t < nb) bsum[t] = s[t] - v;
}

// ---- scan phase 3 ----
__global__ void k_scan3(int* __restrict__ row_part, const int* __restrict__ bsum, int n) {
    int stride = gridDim.x * blockDim.x;
    for (int i = blockIdx.x * blockDim.x + threadIdx.x; i < n; i += stride)
        row_part[i] += bsum[i >> 8];
}

// ---- pass 2: reorder ----
__global__ void k_reorder(const int* __restrict__ src, const int* __restrict__ dst,
                          const int* __restrict__ rank, const int* __restrict__ rowst,
                          int* __restrict__ csr, int E) {
    int e = blockIdx.x * blockDim.x + threadIdx.x;
    if (e >= E) return;
    csr[rowst[dst[e]] + rank[e]] = src[e];
}

// ---- input layer: y0 = bf16( disq * relu(concat(x_cont, emb[ft]) @ W_in + b_in) ) ----
__global__ void k_input(const float* __restrict__ xc, const int* __restrict__ ft,
                        const float* __restrict__ emb, const float* __restrict__ Win,
                        const float* __restrict__ bin, const float* __restrict__ disq,
                        unsigned short* __restrict__ y, int n) {
    int lane = threadIdx.x & 63;
    int wid  = (blockIdx.x * blockDim.x + threadIdx.x) >> 6;
    if (wid >= n) return;
    float acc = bin[lane];
    const float* xr = xc + (size_t)wid * FC;
#pragma unroll
    for (int k = 0; k < FC; k++)
        acc = fmaf(xr[k], Win[k * HD + lane], acc);
    int t = ft[wid];
    const float* er = emb + (size_t)t * FEMB;
#pragma unroll
    for (int k = 0; k < FEMB; k++)
        acc = fmaf(er[k], Win[(FC + k) * HD + lane], acc);
    y[(size_t)wid * HD + lane] = f2bf(fmaxf(acc, 0.0f) * disq[wid]);
}

// ---- aggregation: agg_i = disq_i * (y_i + sum_{j in N(i)} y_j)   [y is bf16] ----
// one wave per node; 8 subgroups of 8 lanes; each subgroup loads one 128B row
// (uint4/lane). 8 edges per load instruction, 2 chunks unrolled = 16 in flight.
__global__ void k_agg(const uint4* __restrict__ y4, const int* __restrict__ csr,
                      const int* __restrict__ rs, const int* __restrict__ deg,
                      const float* __restrict__ disq, float* __restrict__ agg, int n) {
    int lane = threadIdx.x & 63;
    int node = (blockIdx.x * blockDim.x + threadIdx.x) >> 6;
    if (node >= n) return;
    int g = lane >> 3;   // edge subgroup 0..7
    int c = lane & 7;    // uint4 column (8 bf16 cols per lane)
    int start = rs[node];
    int end   = start + deg[node];
    float di  = disq[node];
    float a0 = 0.f, a1 = 0.f, a2 = 0.f, a3 = 0.f;
    float a4 = 0.f, a5 = 0.f, a6 = 0.f, a7 = 0.f;
    for (int j = start; j < end; j += 16) {
        int e0 = j + g, e1 = j + 8 + g;
        bool ok0 = e0 < end, ok1 = e1 < end;
        int s0 = csr[ok0 ? e0 : j];
        int s1 = csr[ok1 ? e1 : j];
        uint4 v0 = y4[(size_t)s0 * 8 + c];
        uint4 v1 = y4[(size_t)s1 * 8 + c];
        if (ok0) {
            a0 += bfu(v0.x << 16); a1 += bfu(v0.x & 0xffff0000u);
            a2 += bfu(v0.y << 16); a3 += bfu(v0.y & 0xffff0000u);
            a4 += bfu(v0.z << 16); a5 += bfu(v0.z & 0xffff0000u);
            a6 += bfu(v0.w << 16); a7 += bfu(v0.w & 0xffff0000u);
        }
        if (ok1) {
            a0 += bfu(v1.x << 16); a1 += bfu(v1.x & 0xffff0000u);
            a2 += bfu(v1.y << 16); a3 += bfu(v1.y & 0xffff0000u);
            a4 += bfu(v1.z << 16); a5 += bfu(v1.z & 0xffff0000u);
            a6 += bfu(v1.w << 16); a7 += bfu(v1.w & 0xffff0000u);
        }
    }
#define RED8(off) \
    a0 += __shfl_xor(a0, off); a1 += __shfl_xor(a1, off); \
    a2 += __shfl_xor(a2, off); a3 += __shfl_xor(a3, off); \
    a4 += __shfl_xor(a4, off); a5 += __shfl_xor(a5, off); \
    a6 += __shfl_xor(a6, off); a7 += __shfl_xor(a7, off);
    RED8(8) RED8(16) RED8(32)
#undef RED8
    if (g == 0) {
        uint4 sv = y4[(size_t)node * 8 + c];
        a0 += bfu(sv.x << 16); a1 += bfu(sv.x & 0xffff0000u);
        a2 += bfu(sv.y << 16); a3 += bfu(sv.y & 0xffff0000u);
        a4 += bfu(sv.z << 16); a5 += bfu(sv.z & 0xffff0000u);
        a6 += bfu(sv.w << 16); a7 += bfu(sv.w & 0xffff0000u);
        float4* ap = (float4*)(agg + (size_t)node * HD + c * 8);
        float4 o1 = {di * a0, di * a1, di * a2, di * a3};
        float4 o2 = {di * a4, di * a5, di * a6, di * a7};
        ap[0] = o1;
        ap[1] = o2;
    }
}

// ---- tiled matmul: y16 = bf16( disq * relu(agg @ W + b) ) ----
__global__ __launch_bounds__(256, 4)
void k_mm(const float* __restrict__ x, const float* __restrict__ W,
          const float* __restrict__ b, const float* __restrict__ disq,
          unsigned short* __restrict__ yo, int n) {
    __shared__ float4 ws4[64][16];
    __shared__ float4 xs4[64][17];
    int tid = threadIdx.x;
    int node0 = blockIdx.x * 64;

    for (int i = tid; i < 1024; i += 256)
        ws4[i >> 4][i & 15] = ((const float4*)W)[i];
    for (int i = tid; i < 1024; i += 256) {
        int nn = i >> 4, k4 = i & 15;
        int row = node0 + nn; if (row >= n) row = n - 1;
        xs4[nn][k4] = ((const float4*)(x + (size_t)row * HD))[k4];
    }
    __syncthreads();

    int tc4 = tid & 15;
    int tn  = (tid >> 4) * 4;
    float4 ac0 = {0,0,0,0}, ac1 = {0,0,0,0}, ac2 = {0,0,0,0}, ac3 = {0,0,0,0};

#pragma unroll 4
    for (int k4 = 0; k4 < 16; k4++) {
        float4 w0 = ws4[k4 * 4 + 0][tc4];
        float4 w1 = ws4[k4 * 4 + 1][tc4];
        float4 w2 = ws4[k4 * 4 + 2][tc4];
        float4 w3 = ws4[k4 * 4 + 3][tc4];
#pragma unroll
        for (int i = 0; i < 4; i++) {
            float4 xv = xs4[tn + i][k4];
            float4* ac = (i == 0) ? &ac0 : (i == 1) ? &ac1 : (i == 2) ? &ac2 : &ac3;
            ac->x = fmaf(xv.x, w0.x, ac->x); ac->y = fmaf(xv.x, w0.y, ac->y);
            ac->z = fmaf(xv.x, w0.z, ac->z); ac->w = fmaf(xv.x, w0.w, ac->w);
            ac->x = fmaf(xv.y, w1.x, ac->x); ac->y = fmaf(xv.y, w1.y, ac->y);
            ac->z = fmaf(xv.y, w1.z, ac->z); ac->w = fmaf(xv.y, w1.w, ac->w);
            ac->x = fmaf(xv.z, w2.x, ac->x); ac->y = fmaf(xv.z, w2.y, ac->y);
            ac->z = fmaf(xv.z, w2.z, ac->z); ac->w = fmaf(xv.z, w2.w, ac->w);
            ac->x = fmaf(xv.w, w3.x, ac->x); ac->y = fmaf(xv.w, w3.y, ac->y);
            ac->z = fmaf(xv.w, w3.z, ac->z); ac->w = fmaf(xv.w, w3.w, ac->w);
        }
    }

    float4 bb = ((const float4*)b)[tc4];
    float4 accs[4] = {ac0, ac1, ac2, ac3};
#pragma unroll
    for (int i = 0; i < 4; i++) {
        int row = node0 + tn + i;
        if (row < n) {
            float dq = disq[row];
            ushort4 o;
            o.x = f2bf(fmaxf(accs[i].x + bb.x, 0.0f) * dq);
            o.y = f2bf(fmaxf(accs[i].y + bb.y, 0.0f) * dq);
            o.z = f2bf(fmaxf(accs[i].z + bb.z, 0.0f) * dq);
            o.w = f2bf(fmaxf(accs[i].w + bb.w, 0.0f) * dq);
            *(ushort4*)(yo + (size_t)row * HD + tc4 * 4) = o;
        }
    }
}

// ---- fused layer-3 matmul + head (reads fp32 agg) ----
__global__ __launch_bounds__(256, 4)
void k_mm_head(const float* __restrict__ x, const float* __restrict__ W,
               const float* __restrict__ b, const float* __restrict__ W1,
               const float* __restrict__ b1, const float* __restrict__ W2,
               const float* __restrict__ b2, float* __restrict__ out, int n) {
    __shared__ float4 ws4[64][16];
    __shared__ float4 xs4[64][17];
    int tid = threadIdx.x;
    int node0 = blockIdx.x * 64;

    for (int i = tid; i < 1024; i += 256)
        ws4[i >> 4][i & 15] = ((const float4*)W)[i];
    for (int i = tid; i < 1024; i += 256) {
        int nn = i >> 4, k4 = i & 15;
        int row = node0 + nn; if (row >= n) row = n - 1;
        xs4[nn][k4] = ((const float4*)(x + (size_t)row * HD))[k4];
    }
    __syncthreads();

    int tc4 = tid & 15;
    int tn  = (tid >> 4) * 4;

    float4 ac0 = {0,0,0,0}, ac1 = {0,0,0,0}, ac2 = {0,0,0,0}, ac3 = {0,0,0,0};
#pragma unroll 4
    for (int k4 = 0; k4 < 16; k4++) {
        float4 w0 = ws4[k4 * 4 + 0][tc4];
        float4 w1 = ws4[k4 * 4 + 1][tc4];
        float4 w2 = ws4[k4 * 4 + 2][tc4];
        float4 w3 = ws4[k4 * 4 + 3][tc4];
#pragma unroll
        for (int i = 0; i < 4; i++) {
            float4 xv = xs4[tn + i][k4];
            float4* ac = (i == 0) ? &ac0 : (i == 1) ? &ac1 : (i == 2) ? &ac2 : &ac3;
            ac->x = fmaf(xv.x, w0.x, ac->x); ac->y = fmaf(xv.x, w0.y, ac->y);
            ac->z = fmaf(xv.x, w0.z, ac->z); ac->w = fmaf(xv.x, w0.w, ac->w);
            ac->x = fmaf(xv.y, w1.x, ac->x); ac->y = fmaf(xv.y, w1.y, ac->y);
            ac->z = fmaf(xv.y, w1.z, ac->z); ac->w = fmaf(xv.y, w1.w, ac->w);
            ac->x = fmaf(xv.z, w2.x, ac->x); ac->y = fmaf(xv.z, w2.y, ac->y);
            ac->z = fmaf(xv.z, w2.z, ac->z); ac->w = fmaf(xv.z, w2.w, ac->w);
            ac->x = fmaf(xv.w, w3.x, ac->x); ac->y = fmaf(xv.w, w3.y, ac->y);
            ac->z = fmaf(xv.w, w3.z, ac->z); ac->w = fmaf(xv.w, w3.w, ac->w);
        }
    }
    __syncthreads();

    {
        float4 bb = ((const float4*)b)[tc4];
        float4 accs[4] = {ac0, ac1, ac2, ac3};
#pragma unroll
        for (int i = 0; i < 4; i++) {
            float4 o;
            o.x = fmaxf(accs[i].x + bb.x, 0.0f);
            o.y = fmaxf(accs[i].y + bb.y, 0.0f);
            o.z = fmaxf(accs[i].z + bb.z, 0.0f);
            o.w = fmaxf(accs[i].w + bb.w, 0.0f);
            xs4[tn + i][tc4] = o;
        }
    }
    for (int i = tid; i < 1024; i += 256)
        ws4[i >> 4][i & 15] = ((const float4*)W1)[i];
    __syncthreads();

    float4 bc0 = {0,0,0,0}, bc1 = {0,0,0,0}, bc2 = {0,0,0,0}, bc3 = {0,0,0,0};
#pragma unroll 4
    for (int k4 = 0; k4 < 16; k4++) {
        float4 w0 = ws4[k4 * 4 + 0][tc4];
        float4 w1 = ws4[k4 * 4 + 1][tc4];
        float4 w2 = ws4[k4 * 4 + 2][tc4];
        float4 w3 = ws4[k4 * 4 + 3][tc4];
#pragma unroll
        for (int i = 0; i < 4; i++) {
            float4 xv = xs4[tn + i][k4];
            float4* ac = (i == 0) ? &bc0 : (i == 1) ? &bc1 : (i == 2) ? &bc2 : &bc3;
            ac->x = fmaf(xv.x, w0.x, ac->x); ac->y = fmaf(xv.x, w0.y, ac->y);
            ac->z = fmaf(xv.x, w0.z, ac->z); ac->w = fmaf(xv.x, w0.w, ac->w);
            ac->x = fmaf(xv.y, w1.x, ac->x); ac->y = fmaf(xv.y, w1.y, ac->y);
            ac->z = fmaf(xv.y, w1.z, ac->z); ac->w = fmaf(xv.y, w1.w, ac->w);
            ac->x = fmaf(xv.z, w2.x, ac->x); ac->y = fmaf(xv.z, w2.y, ac->y);
            ac->z = fmaf(xv.z, w2.z, ac->z); ac->w = fmaf(xv.z, w2.w, ac->w);
            ac->x = fmaf(xv.w, w3.x, ac->x); ac->y = fmaf(xv.w, w3.y, ac->y);
            ac->z = fmaf(xv.w, w3.z, ac->z); ac->w = fmaf(xv.w, w3.w, ac->w);
        }
    }

    float4 b1v = ((const float4*)b1)[tc4];
    float4 w2v = ((const float4*)W2)[tc4];
    float b2v  = b2[0];
    float4 bcs[4] = {bc0, bc1, bc2, bc3};
#pragma unroll
    for (int i = 0; i < 4; i++) {
        float s = fmaxf(bcs[i].x + b1v.x, 0.0f) * w2v.x
                + fmaxf(bcs[i].y + b1v.y, 0.0f) * w2v.y
                + fmaxf(bcs[i].z + b1v.z, 0.0f) * w2v.z
                + fmaxf(bcs[i].w + b1v.w, 0.0f) * w2v.w;
        s += __shfl_xor(s, 1);
        s += __shfl_xor(s, 2);
        s += __shfl_xor(s, 4);
        s += __shfl_xor(s, 8);
        int row = node0 + tn + i;
        if (tc4 == 0 && row < n) out[row] = s + b2v;
    }
}

extern "C" void kernel_launch(void* const* d_in, const int* in_sizes, int n_in,
                              void* d_out, int out_size, void* d_ws, size_t ws_size,
                              hipStream_t stream) {
    const float* x_cont = (const float*)d_in[0];
    const int*   ftyp   = (const int*)d_in[1];
    const int*   eidx   = (const int*)d_in[2];
    const float* emb    = (const float*)d_in[3];
    const float* W_in   = (const float*)d_in[4];
    const float* b_in   = (const float*)d_in[5];
    const float* W_g    = (const float*)d_in[6];
    const float* b_g    = (const float*)d_in[7];
    const float* W_o1   = (const float*)d_in[8];
    const float* b_o1   = (const float*)d_in[9];
    const float* W_o2   = (const float*)d_in[10];
    const float* b_o2   = (const float*)d_in[11];
    float* out = (float*)d_out;

    const int n = in_sizes[1];
    const int E = in_sizes[2] / 2;
    const int* src = eidx;
    const int* dst = eidx + E;

    char* p = (char*)d_ws;
    auto alloc = [&](size_t bytes) {
        char* r = p;
        p += (bytes + 255) & ~(size_t)255;
        return r;
    };
    int*   cnt   = (int*)  alloc((size_t)n * 4);
    float* disq  = (float*)alloc((size_t)n * 4);
    int*   rowst = (int*)  alloc((size_t)n * 4);
    int*   bsum  = (int*)  alloc(4096);
    int*   rank  = (int*)  alloc((size_t)E * 4);
    int*   csr   = (int*)  alloc((size_t)E * 4);
    unsigned short* y16 = (unsigned short*)alloc((size_t)n * HD * 2);
    float* agg   = (float*)alloc((size_t)n * HD * 4);

    hipMemsetAsync(cnt, 0, (size_t)n * 4, stream);

    dim3 blk(256);
    const int nb1   = (n + 255) / 256;
    const int nb_e  = (E + 255) / 256;
    const int nb_nw = (n + 3) / 4;    // one wave per node
    const int nb_t  = (n + 63) / 64;  // 64-node tiles

    k_count_rank<<<nb_e, blk, 0, stream>>>(dst, cnt, rank, E);
    k_scan1<<<nb1, blk, 0, stream>>>(cnt, rowst, bsum, disq, n);
    k_scan2<<<1, 1024, 0, stream>>>(bsum, nb1);
    k_scan3<<<512, blk, 0, stream>>>(rowst, bsum, n);
    k_reorder<<<nb_e, blk, 0, stream>>>(src, dst, rank, rowst, csr, E);
    k_input<<<nb_nw, blk, 0, stream>>>(x_cont, ftyp, emb, W_in, b_in, disq, y16, n);

    for (int L = 0; L < 2; L++) {
        k_agg<<<nb_nw, blk, 0, stream>>>((const uint4*)y16, csr, rowst, cnt, disq, agg, n);
        k_mm<<<nb_t, blk, 0, stream>>>(agg, W_g + (size_t)L * HD * HD,
                                       b_g + (size_t)L * HD, disq, y16, n);
    }
    k_agg<<<nb_nw, blk, 0, stream>>>((const uint4*)y16, csr, rowst, cnt, disq, agg, n);
    k_mm_head<<<nb_t, blk, 0, stream>>>(agg, W_g + (size_t)2 * HD * HD,
                                        b_g + (size_t)2 * HD,
                                        W_o1, b_o1, W_o2, b_o2, out, n);
}